// Round 1
// baseline (2177.773 us; speedup 1.0000x reference)
//
#include <hip/hip_runtime.h>
#include <hip/hip_bf16.h>
#include <cstddef>

#define H 200
#define NA 48
#define NBB 96
#define BATCH 128
#define AFD 39
#define BFD 50          // 39+11
#define LP 1000
#define CATD (AFD + H)  // 239
#define BPB 4           // bonds per block in message kernel
#define APB 2           // atoms per block in atom kernel

// ---------------- zero init ----------------
__global__ void k_zero(float* p, int n) {
    int i = blockIdx.x * blockDim.x + threadIdx.x;
    if (i < n) p[i] = 0.f;
}

// ---------------- binput = fbonds @ W_i ; msg = relu(binput) ----------------
__global__ __launch_bounds__(256) void k_bond_input(
        const float* __restrict__ fbonds, const float* __restrict__ Wi,
        float* __restrict__ binput, float* __restrict__ msg) {
    int bond = blockIdx.x;  // b*NBB + j
    __shared__ float fb[BFD];
    int tid = threadIdx.x;
    if (tid < BFD) fb[tid] = fbonds[(size_t)bond * BFD + tid];
    __syncthreads();
    if (tid < H) {
        float acc = 0.f;
#pragma unroll 10
        for (int k = 0; k < BFD; ++k) acc += fb[k] * Wi[k * H + tid];
        size_t o = (size_t)bond * H + tid;
        binput[o] = acc;
        msg[o] = fmaxf(acc, 0.f);
    }
}

// ---------------- message update: msgOut = relu(binput + (sum nei) @ W_h) ----------------
__global__ __launch_bounds__(256) void k_msg(
        const float* __restrict__ msgIn, const float* __restrict__ binput,
        const int* __restrict__ bgraph, const float* __restrict__ Wh,
        float* __restrict__ msgOut) {
    const int grpPerMol = NBB / BPB;  // 24
    int b = blockIdx.x / grpPerMol;
    int grp = blockIdx.x % grpPerMol;
    int bond0 = grp * BPB;
    __shared__ int idxs[BPB * 6];
    __shared__ float nei[BPB][H];
    int tid = threadIdx.x;
    if (tid < BPB * 6) idxs[tid] = bgraph[((size_t)(b * NBB + bond0)) * 6 + tid];
    __syncthreads();
    if (tid < H) {
        const float* base = msgIn + (size_t)b * NBB * H;
#pragma unroll
        for (int q = 0; q < BPB; ++q) {
            float s = 0.f;
#pragma unroll
            for (int j = 0; j < 6; ++j) s += base[(size_t)idxs[q * 6 + j] * H + tid];
            nei[q][tid] = s;
        }
    }
    __syncthreads();
    if (tid < H) {
        float acc[BPB];
#pragma unroll
        for (int q = 0; q < BPB; ++q)
            acc[q] = binput[((size_t)(b * NBB + bond0 + q)) * H + tid];
#pragma unroll 4
        for (int hi = 0; hi < H; ++hi) {
            float w = Wh[hi * H + tid];
#pragma unroll
            for (int q = 0; q < BPB; ++q) acc[q] += nei[q][hi] * w;
        }
#pragma unroll
        for (int q = 0; q < BPB; ++q)
            msgOut[((size_t)(b * NBB + bond0 + q)) * H + tid] = fmaxf(acc[q], 0.f);
    }
}

// ---------------- atom head: relu(cat(fa, nei) @ W_o + b), mean over atoms -> x[:, :200] ----------------
__global__ __launch_bounds__(256) void k_atom(
        const float* __restrict__ msg, const float* __restrict__ fatoms,
        const int* __restrict__ agraph, const float* __restrict__ Wo,
        const float* __restrict__ Wob, float* __restrict__ x) {
    const int grpPerMol = NA / APB;  // 24
    int b = blockIdx.x / grpPerMol;
    int grp = blockIdx.x % grpPerMol;
    int atom0 = grp * APB;
    __shared__ int idxs[APB * 6];
    __shared__ float cat[APB][CATD];
    int tid = threadIdx.x;
    if (tid < APB * 6) idxs[tid] = agraph[((size_t)(b * NA + atom0)) * 6 + tid];
    if (tid >= 64 && tid < 64 + APB * AFD) {
        int t = tid - 64;
        int q = t / AFD, c = t % AFD;
        cat[q][c] = fatoms[((size_t)(b * NA + atom0 + q)) * AFD + c];
    }
    __syncthreads();
    if (tid < H) {
        const float* base = msg + (size_t)b * NBB * H;
#pragma unroll
        for (int q = 0; q < APB; ++q) {
            float s = 0.f;
#pragma unroll
            for (int j = 0; j < 6; ++j) s += base[(size_t)idxs[q * 6 + j] * H + tid];
            cat[q][AFD + tid] = s;
        }
    }
    __syncthreads();
    if (tid < H) {
        float bb = Wob[tid];
        float acc0 = bb, acc1 = bb;
#pragma unroll 4
        for (int k = 0; k < CATD; ++k) {
            float w = Wo[k * H + tid];
            acc0 += cat[0][k] * w;
            acc1 += cat[1][k] * w;
        }
        atomicAdd(&x[(size_t)b * 400 + tid],
                  (fmaxf(acc0, 0.f) + fmaxf(acc1, 0.f)) * (1.f / NA));
    }
}

// ---------------- protein embedding (gather + transpose to (B, 50, L)) ----------------
__global__ __launch_bounds__(256) void k_embed(
        const int* __restrict__ seq, const float* __restrict__ emb,
        float* __restrict__ pv) {
    int i = blockIdx.x * blockDim.x + threadIdx.x;  // b*LP + l
    if (i >= BATCH * LP) return;
    int b = i / LP, l = i % LP;
    int s = seq[i];
    const float* e = emb + (size_t)s * 50;
    float* o = pv + (size_t)b * 50 * LP + l;
#pragma unroll 10
    for (int c = 0; c < 50; ++c) o[c * LP] = e[c];
}

// ---------------- conv1d (same padding) + relu; optional fused global max over L ----------------
// in: (B, CIN, LP), w: (COUT, CIN, K), out: full map (B, COUT, LP) or x[b*400+200+o] if FMAX
template <int CIN, int K, int COUT, int OB, bool FMAX>
__global__ __launch_bounds__(256) void k_conv(
        const float* __restrict__ in, const float* __restrict__ w,
        const float* __restrict__ bias, float* __restrict__ out) {
    constexpr int OGRP = COUT / OB;
    constexpr int WSZ = OB * CIN * K;
    constexpr int PAD = K / 2;
    int b = blockIdx.x / OGRP;
    int og = blockIdx.x % OGRP;
    __shared__ float wl[WSZ];
    __shared__ float bl[OB];
    int tid = threadIdx.x;
    for (int idx = tid; idx < WSZ; idx += 256) wl[idx] = w[(size_t)og * WSZ + idx];
    if (tid < OB) bl[tid] = bias[og * OB + tid];
    __syncthreads();

    float acc[OB][4];
    int l0 = tid * 4;
    bool active = (tid < LP / 4);
    if (active) {
#pragma unroll
        for (int oo = 0; oo < OB; ++oo)
#pragma unroll
            for (int ll = 0; ll < 4; ++ll) acc[oo][ll] = bl[oo];
        const float* inb = in + (size_t)b * CIN * LP;
        for (int i = 0; i < CIN; ++i) {
            const float* row = inb + (size_t)i * LP;
            float v[K + 3];
#pragma unroll
            for (int t = 0; t < K + 3; ++t) {
                int idx = l0 + t - PAD;
                v[t] = ((unsigned)idx < (unsigned)LP) ? row[idx] : 0.f;
            }
#pragma unroll
            for (int oo = 0; oo < OB; ++oo) {
#pragma unroll
                for (int t = 0; t < K; ++t) {
                    float wv = wl[(oo * CIN + i) * K + t];
                    acc[oo][0] += wv * v[t];
                    acc[oo][1] += wv * v[t + 1];
                    acc[oo][2] += wv * v[t + 2];
                    acc[oo][3] += wv * v[t + 3];
                }
            }
        }
    }
    if (!FMAX) {
        if (active) {
#pragma unroll
            for (int oo = 0; oo < OB; ++oo) {
                float4 r;
                r.x = fmaxf(acc[oo][0], 0.f);
                r.y = fmaxf(acc[oo][1], 0.f);
                r.z = fmaxf(acc[oo][2], 0.f);
                r.w = fmaxf(acc[oo][3], 0.f);
                *(float4*)(out + ((size_t)(b * COUT + og * OB + oo)) * LP + l0) = r;
            }
        }
    } else {
        float m[OB];
#pragma unroll
        for (int oo = 0; oo < OB; ++oo) {
            float mm = 0.f;
            if (active) {
                mm = fmaxf(fmaxf(acc[oo][0], acc[oo][1]),
                           fmaxf(acc[oo][2], acc[oo][3]));
                mm = fmaxf(mm, 0.f);  // relu then max == max then clamp at 0
            }
            m[oo] = mm;
        }
        __shared__ float red[OB][4];
        int lane = tid & 63, wv = tid >> 6;
#pragma unroll
        for (int oo = 0; oo < OB; ++oo) {
            float mm = m[oo];
#pragma unroll
            for (int off = 32; off >= 1; off >>= 1)
                mm = fmaxf(mm, __shfl_down(mm, off, 64));
            if (lane == 0) red[oo][wv] = mm;
        }
        __syncthreads();
        if (tid < OB) {
            float mm = fmaxf(fmaxf(red[tid][0], red[tid][1]),
                             fmaxf(red[tid][2], red[tid][3]));
            out[(size_t)b * 400 + 200 + og * OB + tid] = mm;
        }
    }
}

// ---------------- FC head ----------------
__global__ __launch_bounds__(256) void k_fc0(
        const float* __restrict__ x, const float* __restrict__ w,
        const float* __restrict__ bias, float* __restrict__ h1) {
    int b = blockIdx.x;
    __shared__ float xr[400];
    int tid = threadIdx.x;
    for (int i = tid; i < 400; i += 256) xr[i] = x[(size_t)b * 400 + i];
    __syncthreads();
    if (tid < 200) {
        float acc = bias[tid];
#pragma unroll 4
        for (int k = 0; k < 400; ++k) acc += xr[k] * w[k * 200 + tid];
        h1[(size_t)b * 200 + tid] = fmaxf(acc, 0.f);
    }
}
__global__ __launch_bounds__(128) void k_fc1(
        const float* __restrict__ h1, const float* __restrict__ w,
        const float* __restrict__ bias, float* __restrict__ h2) {
    int b = blockIdx.x;
    __shared__ float xr[200];
    int tid = threadIdx.x;
    for (int i = tid; i < 200; i += 128) xr[i] = h1[(size_t)b * 200 + i];
    __syncthreads();
    if (tid < 100) {
        float acc = bias[tid];
#pragma unroll 4
        for (int k = 0; k < 200; ++k) acc += xr[k] * w[k * 100 + tid];
        h2[(size_t)b * 100 + tid] = fmaxf(acc, 0.f);
    }
}
__global__ __launch_bounds__(128) void k_fc2(
        const float* __restrict__ h2, const float* __restrict__ w,
        const float* __restrict__ bias, float* __restrict__ out) {
    int b = blockIdx.x * blockDim.x + threadIdx.x;
    if (b < BATCH) {
        float acc = bias[0];
#pragma unroll 4
        for (int k = 0; k < 100; ++k) acc += h2[(size_t)b * 100 + k] * w[k];
        out[b] = acc;
    }
}

extern "C" void kernel_launch(void* const* d_in, const int* in_sizes, int n_in,
                              void* d_out, int out_size, void* d_ws, size_t ws_size,
                              hipStream_t stream) {
    const float* fatoms = (const float*)d_in[0];
    const float* fbonds = (const float*)d_in[1];
    const int* agraph = (const int*)d_in[2];
    const int* bgraph = (const int*)d_in[3];
    const int* seq = (const int*)d_in[4];
    const float* Wi = (const float*)d_in[5];
    const float* Wh = (const float*)d_in[6];
    const float* Wo = (const float*)d_in[7];
    const float* Wob = (const float*)d_in[8];
    const float* embp = (const float*)d_in[9];
    const float* c0w = (const float*)d_in[10];
    const float* c0b = (const float*)d_in[11];
    const float* c1w = (const float*)d_in[12];
    const float* c1b = (const float*)d_in[13];
    const float* c2w = (const float*)d_in[14];
    const float* c2b = (const float*)d_in[15];
    const float* fc0w = (const float*)d_in[16];
    const float* fc0b = (const float*)d_in[17];
    const float* fc1w = (const float*)d_in[18];
    const float* fc1b = (const float*)d_in[19];
    const float* fc2w = (const float*)d_in[20];
    const float* fc2b = (const float*)d_in[21];

    float* ws = (float*)d_ws;
    float* binput = ws;                        // 128*96*200 = 2457600
    float* msgA = binput + 2457600;            // 2457600
    float* msgB = msgA + 2457600;              // 2457600
    float* x = msgB + 2457600;                 // 128*400 = 51200
    float* h1 = x + 51200;                     // 25600
    float* h2 = h1 + 25600;                    // 12800
    float* bufA = h2 + 12800;                  // 128*128*1000 = 16384000 (pv0 + conv1 out)
    float* bufB = bufA + 16384000;             // 128*96*1000 = 12288000 (conv0 out)

    // x must be zeroed: atom kernel atomically accumulates the first 200 cols.
    k_zero<<<(51200 + 255) / 256, 256, 0, stream>>>(x, 51200);

    // ---- MPNN ----
    k_bond_input<<<BATCH * NBB, 256, 0, stream>>>(fbonds, Wi, binput, msgA);
    k_msg<<<BATCH * NBB / BPB, 256, 0, stream>>>(msgA, binput, bgraph, Wh, msgB);
    k_msg<<<BATCH * NBB / BPB, 256, 0, stream>>>(msgB, binput, bgraph, Wh, msgA);
    k_atom<<<BATCH * NA / APB, 256, 0, stream>>>(msgA, fatoms, agraph, Wo, Wob, x);

    // ---- protein tower ----
    k_embed<<<(BATCH * LP + 255) / 256, 256, 0, stream>>>(seq, embp, bufA);
    k_conv<50, 3, 96, 4, false><<<BATCH * (96 / 4), 256, 0, stream>>>(bufA, c0w, c0b, bufB);
    k_conv<96, 5, 128, 4, false><<<BATCH * (128 / 4), 256, 0, stream>>>(bufB, c1w, c1b, bufA);
    k_conv<128, 7, 200, 4, true><<<BATCH * (200 / 4), 256, 0, stream>>>(bufA, c2w, c2b, x);

    // ---- FC head ----
    k_fc0<<<BATCH, 256, 0, stream>>>(x, fc0w, fc0b, h1);
    k_fc1<<<BATCH, 128, 0, stream>>>(h1, fc1w, fc1b, h2);
    k_fc2<<<1, 128, 0, stream>>>(h2, fc2w, fc2b, (float*)d_out);
}

// Round 2
// 430.337 us; speedup vs baseline: 5.0606x; 5.0606x over previous
//
#include <hip/hip_runtime.h>
#include <hip/hip_bf16.h>
#include <cstddef>

#define H 200
#define NA 48
#define NBB 96
#define BATCH 128
#define AFD 39
#define BFD 50          // 39+11
#define LP 1000
#define CATD (AFD + H)  // 239
#define BPB 4           // bonds per block in message kernel
#define APB 2           // atoms per block in atom kernel

typedef unsigned short ushort_t;
typedef __bf16 bf16x8 __attribute__((ext_vector_type(8)));
typedef float f32x4 __attribute__((ext_vector_type(4)));

union U16B { uint4 u; bf16x8 b; };
static __device__ __forceinline__ bf16x8 as_bf16x8(uint4 u) { U16B x; x.u = u; return x.b; }

// float -> bf16 (RNE)
static __device__ __forceinline__ ushort_t f2bf(float f) {
    union { float f; unsigned u; } a; a.f = f;
    unsigned r = (a.u + 0x7FFFu + ((a.u >> 16) & 1u)) >> 16;
    return (ushort_t)r;
}

// ---------------- zero init ----------------
__global__ void k_zero(float* p, int n) {
    int i = blockIdx.x * blockDim.x + threadIdx.x;
    if (i < n) p[i] = 0.f;
}

// ---------------- weight swizzle to per-lane MFMA fragment order ----------------
// Wb[((ct*NS + s)*64 + lane)*8 + j] = bf16(w[co][ci][t]) with
//   co = ct*16 + (lane&15), t = s/NC, cc = s%NC, ci = cc*32 + (lane>>4)*8 + j
template <int COUT, int CIN, int CP, int K, int NT16>
__global__ __launch_bounds__(256) void k_prep_w(
        const float* __restrict__ w, ushort_t* __restrict__ Wb) {
    constexpr int NC = CP / 32;
    constexpr int NS = K * NC;
    constexpr int TOT = NT16 * NS * 512;
    int tid = blockIdx.x * blockDim.x + threadIdx.x;
    if (tid >= TOT) return;
    int j = tid & 7;
    int lane = (tid >> 3) & 63;
    int s = (tid >> 9) % NS;
    int ct = tid >> 9;
    ct /= NS;
    int co = ct * 16 + (lane & 15);
    int t = s / NC, cc = s % NC;
    int ci = cc * 32 + ((lane >> 4) & 3) * 8 + j;
    float v = 0.f;
    if (co < COUT && ci < CIN) v = w[((size_t)co * CIN + ci) * K + t];
    Wb[tid] = f2bf(v);
}

// ---------------- protein embedding -> channel-last bf16 (B, L, 64) ----------------
__global__ __launch_bounds__(256) void k_embed_bf(
        const int* __restrict__ seq, const float* __restrict__ emb,
        ushort_t* __restrict__ act0) {
    int tid = blockIdx.x * blockDim.x + threadIdx.x;  // (b*L + l)*8 + chunk
    if (tid >= BATCH * LP * 8) return;
    int i = tid >> 3;
    int c0 = (tid & 7) * 8;
    int s = seq[i];
    const float* e = emb + (size_t)s * 50;
    ushort_t h[8];
#pragma unroll
    for (int j = 0; j < 8; ++j) {
        int c = c0 + j;
        h[j] = (c < 50) ? f2bf(e[c]) : (ushort_t)0;
    }
    uint4 o;
    o.x = (unsigned)h[0] | ((unsigned)h[1] << 16);
    o.y = (unsigned)h[2] | ((unsigned)h[3] << 16);
    o.z = (unsigned)h[4] | ((unsigned)h[5] << 16);
    o.w = (unsigned)h[6] | ((unsigned)h[7] << 16);
    *(uint4*)(act0 + (size_t)i * 64 + c0) = o;
}

// ---------------- MFMA conv1d, channel-last bf16, same padding ----------------
// in: (B, LP, CP) bf16. weights pre-swizzled. If !FMAX: out (B, LP, COUT) bf16.
// If FMAX: relu + global max over L -> atomicMax into xout[b*400 + 200 + co].
// Block: 4 waves = 32 co x 128 l. Grid: (l_blocks=8, co_blocks=ceil(COUT/32), B).
template <int CP, int K, int COUT, bool FMAX>
__global__ __launch_bounds__(256) void k_conv_mfma(
        const ushort_t* __restrict__ act, const ushort_t* __restrict__ Wb,
        const float* __restrict__ bias, void* __restrict__ outv) {
    constexpr int NC = CP / 32;
    constexpr int NS = K * NC;
    constexpr int P = K / 2;
    constexpr int PITCH = CP + 8;       // ushorts; bytes multiple of 16
    constexpr int ROWS = 128 + K - 1;
    __shared__ __align__(16) ushort_t Xs[ROWS * PITCH];

    int b = blockIdx.z, ct2 = blockIdx.y, lb = blockIdx.x;
    int l0 = lb * 128;
    int tid = threadIdx.x;

    // ---- stage X tile (with halo, zero-padded at edges) ----
    constexpr int CPR = CP / 8;         // 16B chunks per row
    constexpr int TOT = ROWS * CPR;
    const ushort_t* actb = act + (size_t)b * LP * CP;
    for (int idx = tid; idx < TOT; idx += 256) {
        int r = idx / CPR, c = idx % CPR;
        int l = l0 - P + r;
        uint4 v = {0u, 0u, 0u, 0u};
        if ((unsigned)l < (unsigned)LP) v = *(const uint4*)(actb + (size_t)l * CP + c * 8);
        *(uint4*)(Xs + r * PITCH + c * 8) = v;
    }

    // ---- preload A fragments (weights) into registers ----
    int lane = tid & 63, wv = tid >> 6;
    int co_sub = wv >> 1, l_sub = wv & 1;
    int ct16 = ct2 * 2 + co_sub;
    uint4 wf[NS];
    const uint4* wbase = (const uint4*)(Wb + ((size_t)ct16 * NS * 64 + lane) * 8);
#pragma unroll
    for (int s = 0; s < NS; ++s) wf[s] = wbase[(size_t)s * 64];

    __syncthreads();

    int quad = lane >> 4, ln = lane & 15;
    int lbase = l_sub * 64 + ln;
    f32x4 acc[4];
#pragma unroll
    for (int nt = 0; nt < 4; ++nt) acc[nt] = f32x4{0.f, 0.f, 0.f, 0.f};

#pragma unroll
    for (int s = 0; s < NS; ++s) {
        int t = s / NC, cc = s % NC;
        int coff = cc * 32 + quad * 8;
#pragma unroll
        for (int nt = 0; nt < 4; ++nt) {
            uint4 bv = *(const uint4*)(Xs + (lbase + nt * 16 + t) * PITCH + coff);
            acc[nt] = __builtin_amdgcn_mfma_f32_16x16x32_bf16(
                as_bf16x8(wf[s]), as_bf16x8(bv), acc[nt], 0, 0, 0);
        }
    }

    int co_l = ct2 * 32 + co_sub * 16 + quad * 4;  // this lane's 4 consecutive co
    if (!FMAX) {
        float4 bv = *(const float4*)(bias + co_l);
        ushort_t* out = (ushort_t*)outv + (size_t)b * LP * COUT;
#pragma unroll
        for (int nt = 0; nt < 4; ++nt) {
            int lg = l0 + lbase + nt * 16;
            if (lg < LP) {
                ushort_t h0 = f2bf(fmaxf(acc[nt][0] + bv.x, 0.f));
                ushort_t h1 = f2bf(fmaxf(acc[nt][1] + bv.y, 0.f));
                ushort_t h2 = f2bf(fmaxf(acc[nt][2] + bv.z, 0.f));
                ushort_t h3 = f2bf(fmaxf(acc[nt][3] + bv.w, 0.f));
                uint2 o;
                o.x = (unsigned)h0 | ((unsigned)h1 << 16);
                o.y = (unsigned)h2 | ((unsigned)h3 << 16);
                *(uint2*)(out + (size_t)lg * COUT + co_l) = o;
            }
        }
    } else {
        float b0 = 0.f, b1 = 0.f, b2 = 0.f, b3 = 0.f;
        if (co_l + 3 < COUT) {
            float4 bv = *(const float4*)(bias + co_l);
            b0 = bv.x; b1 = bv.y; b2 = bv.z; b3 = bv.w;
        }
        float mx[4] = {0.f, 0.f, 0.f, 0.f};
#pragma unroll
        for (int nt = 0; nt < 4; ++nt) {
            int lg = l0 + lbase + nt * 16;
            if (lg < LP) {
                mx[0] = fmaxf(mx[0], acc[nt][0] + b0);
                mx[1] = fmaxf(mx[1], acc[nt][1] + b1);
                mx[2] = fmaxf(mx[2], acc[nt][2] + b2);
                mx[3] = fmaxf(mx[3], acc[nt][3] + b3);
            }
        }
#pragma unroll
        for (int r = 0; r < 4; ++r) {
#pragma unroll
            for (int off = 1; off < 16; off <<= 1)
                mx[r] = fmaxf(mx[r], __shfl_xor(mx[r], off, 64));
        }
        if (ln == 0) {
            float* xout = (float*)outv;
#pragma unroll
            for (int r = 0; r < 4; ++r) {
                int co = co_l + r;
                if (co < COUT)
                    atomicMax((int*)&xout[(size_t)b * 400 + 200 + co],
                              __float_as_int(fmaxf(mx[r], 0.f)));
            }
        }
    }
}

// ---------------- binput = fbonds @ W_i ; msg = relu(binput) ----------------
__global__ __launch_bounds__(256) void k_bond_input(
        const float* __restrict__ fbonds, const float* __restrict__ Wi,
        float* __restrict__ binput, float* __restrict__ msg) {
    int bond = blockIdx.x;
    __shared__ float fb[BFD];
    int tid = threadIdx.x;
    if (tid < BFD) fb[tid] = fbonds[(size_t)bond * BFD + tid];
    __syncthreads();
    if (tid < H) {
        float acc = 0.f;
#pragma unroll 10
        for (int k = 0; k < BFD; ++k) acc += fb[k] * Wi[k * H + tid];
        size_t o = (size_t)bond * H + tid;
        binput[o] = acc;
        msg[o] = fmaxf(acc, 0.f);
    }
}

// ---------------- message update ----------------
__global__ __launch_bounds__(256) void k_msg(
        const float* __restrict__ msgIn, const float* __restrict__ binput,
        const int* __restrict__ bgraph, const float* __restrict__ Wh,
        float* __restrict__ msgOut) {
    const int grpPerMol = NBB / BPB;
    int b = blockIdx.x / grpPerMol;
    int grp = blockIdx.x % grpPerMol;
    int bond0 = grp * BPB;
    __shared__ int idxs[BPB * 6];
    __shared__ float nei[BPB][H];
    int tid = threadIdx.x;
    if (tid < BPB * 6) idxs[tid] = bgraph[((size_t)(b * NBB + bond0)) * 6 + tid];
    __syncthreads();
    if (tid < H) {
        const float* base = msgIn + (size_t)b * NBB * H;
#pragma unroll
        for (int q = 0; q < BPB; ++q) {
            float s = 0.f;
#pragma unroll
            for (int j = 0; j < 6; ++j) s += base[(size_t)idxs[q * 6 + j] * H + tid];
            nei[q][tid] = s;
        }
    }
    __syncthreads();
    if (tid < H) {
        float acc[BPB];
#pragma unroll
        for (int q = 0; q < BPB; ++q)
            acc[q] = binput[((size_t)(b * NBB + bond0 + q)) * H + tid];
#pragma unroll 4
        for (int hi = 0; hi < H; ++hi) {
            float w = Wh[hi * H + tid];
#pragma unroll
            for (int q = 0; q < BPB; ++q) acc[q] += nei[q][hi] * w;
        }
#pragma unroll
        for (int q = 0; q < BPB; ++q)
            msgOut[((size_t)(b * NBB + bond0 + q)) * H + tid] = fmaxf(acc[q], 0.f);
    }
}

// ---------------- atom head ----------------
__global__ __launch_bounds__(256) void k_atom(
        const float* __restrict__ msg, const float* __restrict__ fatoms,
        const int* __restrict__ agraph, const float* __restrict__ Wo,
        const float* __restrict__ Wob, float* __restrict__ x) {
    const int grpPerMol = NA / APB;
    int b = blockIdx.x / grpPerMol;
    int grp = blockIdx.x % grpPerMol;
    int atom0 = grp * APB;
    __shared__ int idxs[APB * 6];
    __shared__ float cat[APB][CATD];
    int tid = threadIdx.x;
    if (tid < APB * 6) idxs[tid] = agraph[((size_t)(b * NA + atom0)) * 6 + tid];
    if (tid >= 64 && tid < 64 + APB * AFD) {
        int t = tid - 64;
        int q = t / AFD, c = t % AFD;
        cat[q][c] = fatoms[((size_t)(b * NA + atom0 + q)) * AFD + c];
    }
    __syncthreads();
    if (tid < H) {
        const float* base = msg + (size_t)b * NBB * H;
#pragma unroll
        for (int q = 0; q < APB; ++q) {
            float s = 0.f;
#pragma unroll
            for (int j = 0; j < 6; ++j) s += base[(size_t)idxs[q * 6 + j] * H + tid];
            cat[q][AFD + tid] = s;
        }
    }
    __syncthreads();
    if (tid < H) {
        float bb = Wob[tid];
        float acc0 = bb, acc1 = bb;
#pragma unroll 4
        for (int k = 0; k < CATD; ++k) {
            float w = Wo[k * H + tid];
            acc0 += cat[0][k] * w;
            acc1 += cat[1][k] * w;
        }
        atomicAdd(&x[(size_t)b * 400 + tid],
                  (fmaxf(acc0, 0.f) + fmaxf(acc1, 0.f)) * (1.f / NA));
    }
}

// ---------------- FC head ----------------
__global__ __launch_bounds__(256) void k_fc0(
        const float* __restrict__ x, const float* __restrict__ w,
        const float* __restrict__ bias, float* __restrict__ h1) {
    int b = blockIdx.x;
    __shared__ float xr[400];
    int tid = threadIdx.x;
    for (int i = tid; i < 400; i += 256) xr[i] = x[(size_t)b * 400 + i];
    __syncthreads();
    if (tid < 200) {
        float acc = bias[tid];
#pragma unroll 4
        for (int k = 0; k < 400; ++k) acc += xr[k] * w[k * 200 + tid];
        h1[(size_t)b * 200 + tid] = fmaxf(acc, 0.f);
    }
}
__global__ __launch_bounds__(128) void k_fc1(
        const float* __restrict__ h1, const float* __restrict__ w,
        const float* __restrict__ bias, float* __restrict__ h2) {
    int b = blockIdx.x;
    __shared__ float xr[200];
    int tid = threadIdx.x;
    for (int i = tid; i < 200; i += 128) xr[i] = h1[(size_t)b * 200 + i];
    __syncthreads();
    if (tid < 100) {
        float acc = bias[tid];
#pragma unroll 4
        for (int k = 0; k < 200; ++k) acc += xr[k] * w[k * 100 + tid];
        h2[(size_t)b * 100 + tid] = fmaxf(acc, 0.f);
    }
}
__global__ __launch_bounds__(128) void k_fc2(
        const float* __restrict__ h2, const float* __restrict__ w,
        const float* __restrict__ bias, float* __restrict__ out) {
    int b = blockIdx.x * blockDim.x + threadIdx.x;
    if (b < BATCH) {
        float acc = bias[0];
#pragma unroll 4
        for (int k = 0; k < 100; ++k) acc += h2[(size_t)b * 100 + k] * w[k];
        out[b] = acc;
    }
}

extern "C" void kernel_launch(void* const* d_in, const int* in_sizes, int n_in,
                              void* d_out, int out_size, void* d_ws, size_t ws_size,
                              hipStream_t stream) {
    const float* fatoms = (const float*)d_in[0];
    const float* fbonds = (const float*)d_in[1];
    const int* agraph = (const int*)d_in[2];
    const int* bgraph = (const int*)d_in[3];
    const int* seq = (const int*)d_in[4];
    const float* Wi = (const float*)d_in[5];
    const float* Wh = (const float*)d_in[6];
    const float* Wo = (const float*)d_in[7];
    const float* Wob = (const float*)d_in[8];
    const float* embp = (const float*)d_in[9];
    const float* c0w = (const float*)d_in[10];
    const float* c0b = (const float*)d_in[11];
    const float* c1w = (const float*)d_in[12];
    const float* c1b = (const float*)d_in[13];
    const float* c2w = (const float*)d_in[14];
    const float* c2b = (const float*)d_in[15];
    const float* fc0w = (const float*)d_in[16];
    const float* fc0b = (const float*)d_in[17];
    const float* fc1w = (const float*)d_in[18];
    const float* fc1b = (const float*)d_in[19];
    const float* fc2w = (const float*)d_in[20];
    const float* fc2b = (const float*)d_in[21];

    float* ws = (float*)d_ws;
    float* binput = ws;                    // 2457600
    float* msgA = binput + 2457600;        // 2457600
    float* msgB = msgA + 2457600;          // 2457600
    float* x = msgB + 2457600;             // 51200
    float* h1 = x + 51200;                 // 25600
    float* h2 = h1 + 25600;                // 12800
    ushort_t* u = (ushort_t*)(h2 + 12800); // bf16 region
    ushort_t* act0 = u;                    // 128000*64  = 8192000
    ushort_t* act1 = act0 + 8192000;       // 128000*96  = 12288000
    ushort_t* act2 = act1 + 12288000;      // 128000*128 = 16384000
    ushort_t* Wb0 = act2 + 16384000;       // 6*6*512   = 18432
    ushort_t* Wb1 = Wb0 + 18432;           // 8*15*512  = 61440
    ushort_t* Wb2 = Wb1 + 61440;           // 14*28*512 = 200704

    // x zeroed: k_atom accumulates cols 0..199, conv2 atomicMax cols 200..399.
    k_zero<<<(51200 + 255) / 256, 256, 0, stream>>>(x, 51200);

    // weight swizzles
    k_prep_w<96, 50, 64, 3, 6><<<(6 * 6 * 512 + 255) / 256, 256, 0, stream>>>(c0w, Wb0);
    k_prep_w<128, 96, 96, 5, 8><<<(8 * 15 * 512 + 255) / 256, 256, 0, stream>>>(c1w, Wb1);
    k_prep_w<200, 128, 128, 7, 14><<<(14 * 28 * 512 + 255) / 256, 256, 0, stream>>>(c2w, Wb2);

    // ---- MPNN ----
    k_bond_input<<<BATCH * NBB, 256, 0, stream>>>(fbonds, Wi, binput, msgA);
    k_msg<<<BATCH * NBB / BPB, 256, 0, stream>>>(msgA, binput, bgraph, Wh, msgB);
    k_msg<<<BATCH * NBB / BPB, 256, 0, stream>>>(msgB, binput, bgraph, Wh, msgA);
    k_atom<<<BATCH * NA / APB, 256, 0, stream>>>(msgA, fatoms, agraph, Wo, Wob, x);

    // ---- protein tower (bf16 MFMA) ----
    k_embed_bf<<<(BATCH * LP * 8 + 255) / 256, 256, 0, stream>>>(seq, embp, act0);
    k_conv_mfma<64, 3, 96, false><<<dim3(8, 3, BATCH), 256, 0, stream>>>(act0, Wb0, c0b, act1);
    k_conv_mfma<96, 5, 128, false><<<dim3(8, 4, BATCH), 256, 0, stream>>>(act1, Wb1, c1b, act2);
    k_conv_mfma<128, 7, 200, true><<<dim3(8, 7, BATCH), 256, 0, stream>>>(act2, Wb2, c2b, x);

    // ---- FC head ----
    k_fc0<<<BATCH, 256, 0, stream>>>(x, fc0w, fc0b, h1);
    k_fc1<<<BATCH, 128, 0, stream>>>(h1, fc1w, fc1b, h2);
    k_fc2<<<1, 128, 0, stream>>>(h2, fc2w, fc2b, (float*)d_out);
}